// Round 10
// baseline (14.309 us; speedup 1.0000x reference)
//
#include <hip/hip_runtime.h>
#include <math.h>

#define KTOT 4096
#define BNUM 64
#define MNUM 64
#define NITER 8

// packed lower-tri index (j<=i)
#define LIDX(i,j) ((i)*((i)+1)/2 + (j))

__device__ const float c_cls_mean[3][3] = {
    {1.76255119f, 0.66068622f, 0.84422524f},
    {1.52563191462f, 1.62856739989f, 3.88311640418f},
    {1.73698127f, 0.59706367f, 1.76282397f}
};

// symmetric-3x3 packed access: (0,0)=0 (0,1)=1 (0,2)=2 (1,1)=3 (1,2)=4 (2,2)=5
__device__ __forceinline__ double sym3(const double* a, int i, int j) {
    const int lo = i < j ? i : j, hi = i < j ? j : i;
    return a[lo == 0 ? hi : (lo == 1 ? hi + 2 : 5)];
}
// Full Gram accessor from the 24 unique entries.
// G = [[B, 0, U],[0, B, V],[U^T, V^T, D]]  (U,V stored WITH the minus sign)
__device__ __forceinline__ double Gat(const double* B, const double* U,
                                      const double* V, const double* D,
                                      int i, int j) {
    if (j < i) { const int t = i; i = j; j = t; }
    if (j < 3)  return sym3(B, i, j);
    if (j < 6)  return (i < 3) ? 0.0 : sym3(B, i - 3, j - 3);
    if (i < 3)  return sym3(U, i, j - 6);
    if (i < 6)  return sym3(V, i - 3, j - 6);
    return sym3(D, i - 6, j - 6);
}

// pairwise (tree) dot: forces balanced f64 add tree (compiler must respect
// parenthesization for non-associative f64)
template<int OFF, int N>
__device__ __forceinline__ double tdot(const double* a, const double* b) {
    if constexpr (N == 1) return a[OFF]*b[OFF];
    else if constexpr (N == 2) return a[OFF]*b[OFF] + a[OFF+1]*b[OFF+1];
    else { constexpr int M = N/2; return tdot<OFF,M>(a,b) + tdot<OFF+M,N-M>(a,b); }
}

// LDL^T row recursion (all indices compile-time; tree dots)
template<int I, int J>
__device__ __forceinline__ void fact_j(const double* B, const double* U,
                                       const double* V, const double* Dm,
                                       double* Lf, double* Dinv, double* w, double& diag) {
    if constexpr (J < I) {
        double s = Gat(B, U, V, Dm, J, I);
        if constexpr (J > 0) s -= tdot<0, J>(&Lf[LIDX(J,0)], w);
        const double lij = s * Dinv[J];
        Lf[LIDX(I,J)] = lij;
        w[J] = s;
        diag -= lij * s;
        fact_j<I, J+1>(B, U, V, Dm, Lf, Dinv, w, diag);
    }
}
template<int I>
__device__ __forceinline__ void fact_rows(const double* B, const double* U,
                                          const double* V, const double* Dm,
                                          double* Lf, double* Dinv, double guard) {
    if constexpr (I < 9) {
        double w[9];
        double diag = Gat(B, U, V, Dm, I, I);
        fact_j<I, 0>(B, U, V, Dm, Lf, Dinv, w, diag);
        Dinv[I] = 1.0 / fmax(diag, guard);
        fact_rows<I+1>(B, U, V, Dm, Lf, Dinv, guard);
    }
}

// Compute the 5 Qpred (x,z) points for element k under combo c (f32, matches JAX).
__device__ __forceinline__ void compute_qpred(
    int k, int combo,
    const float* __restrict__ center, const int* __restrict__ cls_ids,
    const float* __restrict__ ry, const float* __restrict__ size3d,
    const float* __restrict__ off_gt, const float* __restrict__ dep_gt,
    const float* __restrict__ out_off, const float* __restrict__ out_dep,
    const float* __restrict__ calibs, const float* __restrict__ trans_inv,
    float* qx, float* qz)
{
    const int b = k >> 6;
    const float cx = center[2*k];
    const int cid = cls_ids[k];
    const float d1 = size3d[3*k+1] + c_cls_mean[cid][1];
    const float d2 = size3d[3*k+2] + c_cls_mean[cid][2];
    float sn, cs;
    sincosf(ry[k], &sn, &cs);

    const float* C = calibs + b*12;
    const float f  = C[0];
    const float cu = C[2];
    const float tx = C[3];
    const float t_x = -tx / f;

    const float* TI = trans_inv + b*6;
    const float s   = TI[0];
    const float t0x = TI[2];

    float ox, dep;
    if (combo == 0)      { ox = off_gt[2*k];  dep = out_dep[k]; }
    else if (combo == 1) { ox = out_off[2*k]; dep = dep_gt[k]; }
    else                 { ox = out_off[2*k]; dep = out_dep[k]; }

    const float uv4x = (cx + ox) * 4.0f;
    const float projx = s * uv4x + t0x;
    const float px = (projx - cu) * dep / f + t_x;
    const float Px = px;
    const float Pz = dep;

    const float r1t[4] = {0.5f, -0.5f, -0.5f, 0.5f};
    const float r2t[4] = {0.5f,  0.5f, -0.5f, -0.5f};
    qx[0] = Px; qz[0] = Pz;
    #pragma unroll
    for (int n = 0; n < 4; ++n) {
        const float sx = d2 * r2t[n];
        const float sz = d1 * r1t[n];
        qx[n+1] = Px + (cs*sx + sn*sz);
        qz[n+1] = Pz + (-sn*sx + cs*sz);
    }
}

__device__ __forceinline__ double sl1(double p, double t) {
    double d = p - t, ad = fabs(d);
    return ad < 1.0 ? 0.5*d*d : ad - 0.5;
}

// One block = one (batch, combo). Gram (24 unique) -> redundant per-lane
// LDL^T + inverse iteration (tree-structured dependent chains) -> masked loss.
__global__ __launch_bounds__(64, 1) void fused_kernel(
    const float* __restrict__ center, const int* __restrict__ cls_ids,
    const float* __restrict__ ry, const float* __restrict__ size3d,
    const float* __restrict__ Pgt, const float* __restrict__ Qgt,
    const float* __restrict__ off_gt, const float* __restrict__ dep_gt,
    const float* __restrict__ out_off, const float* __restrict__ out_dep,
    const float* __restrict__ calibs, const float* __restrict__ trans_inv,
    double* __restrict__ partials)
{
    const int b = blockIdx.x, combo = blockIdx.y;
    const int m = threadIdx.x;
    const int k = (b << 6) + m;

    float qx[5], qz[5];
    compute_qpred(k, combo, center, cls_ids, ry, size3d,
                  off_gt, dep_gt, out_off, out_dep, calibs, trans_inv, qx, qz);

    // ---- early loads: Pgt + Qgt into registers ----
    double Px[5], Py[5];
    float gxr[5], gzr[5];
    #pragma unroll
    for (int p = 0; p < 5; ++p) {
        const float2 P2 = *reinterpret_cast<const float2*>(&Pgt[(k*5+p)*2]);
        Px[p] = (double)P2.x;
        Py[p] = (double)P2.y;
        gxr[p] = Qgt[(k*5+p)*3 + 0];
        gzr[p] = Qgt[(k*5+p)*3 + 2];
    }

    // ---- Gram accumulation: 24 unique entries (B, U=-S_u, V=-S_v, D) ----
    double B[6], U[6], V[6], D[6];
    #pragma unroll
    for (int i = 0; i < 6; ++i) { B[i]=0.0; U[i]=0.0; V[i]=0.0; D[i]=0.0; }

    #pragma unroll
    for (int p = 0; p < 5; ++p) {
        const double x = Px[p];
        const double y = Py[p];
        const double u = (double)qx[p];
        const double v = (double)qz[p];
        const double w[6] = {x*x, x*y, x, y*y, y, 1.0};  // P (x) P packed sym
        const double uv2 = u*u + v*v;
        #pragma unroll
        for (int i = 0; i < 6; ++i) {
            B[i] += w[i];
            U[i] -= w[i]*u;
            V[i] -= w[i]*v;
            D[i] += w[i]*uv2;
        }
    }

    // ---- butterfly reduce (all lanes get full unique-Gram): 24 x 6 shfl ----
    #pragma unroll
    for (int off = 32; off > 0; off >>= 1) {
        #pragma unroll
        for (int i = 0; i < 6; ++i) {
            B[i] += __shfl_xor(B[i], off);
            U[i] += __shfl_xor(U[i], off);
            V[i] += __shfl_xor(V[i], off);
            D[i] += __shfl_xor(D[i], off);
        }
    }

    // ---- ridge shift on the diagonal (eigenvectors unchanged) ----
    double gmax = fmax(fmax(B[0], B[3]), fmax(B[5], fmax(D[0], fmax(D[3], D[5]))));
    const double ridge = 1e-10 * gmax;
    B[0] += ridge; B[3] += ridge; B[5] += ridge;
    D[0] += ridge; D[3] += ridge; D[5] += ridge;

    // ---- LDL^T (no f64 sqrt; tree-structured row dots) ----
    double Lf[45], Dinv[9];
    fact_rows<0>(B, U, V, D, Lf, Dinv, ridge * 1e-2);

    // ---- inverse iteration, UNNORMALIZED; hand-skewed tree solves.
    //      Newest operand sits at the tree root -> ~const cost per level. ----
    double x0 = 1.0,    x1 = 1.0625, x2 = 1.125, x3 = 1.1875, x4 = 1.25,
           x5 = 1.3125, x6 = 1.375,  x7 = 1.4375, x8 = 1.5;

    #pragma unroll 1
    for (int it = 0; it < NITER; ++it) {
        // fwd: y = L^{-1} x  (unit lower)
        const double y0 = x0;
        const double y1 = x1 - Lf[LIDX(1,0)]*y0;
        const double y2 = x2 - (Lf[LIDX(2,0)]*y0 + Lf[LIDX(2,1)]*y1);
        const double y3 = x3 - ((Lf[LIDX(3,0)]*y0 + Lf[LIDX(3,1)]*y1) + Lf[LIDX(3,2)]*y2);
        const double y4 = x4 - ((Lf[LIDX(4,0)]*y0 + Lf[LIDX(4,1)]*y1)
                              + (Lf[LIDX(4,2)]*y2 + Lf[LIDX(4,3)]*y3));
        const double y5 = x5 - (((Lf[LIDX(5,0)]*y0 + Lf[LIDX(5,1)]*y1)
                               + (Lf[LIDX(5,2)]*y2 + Lf[LIDX(5,3)]*y3)) + Lf[LIDX(5,4)]*y4);
        const double y6 = x6 - (((Lf[LIDX(6,0)]*y0 + Lf[LIDX(6,1)]*y1)
                               + (Lf[LIDX(6,2)]*y2 + Lf[LIDX(6,3)]*y3))
                               + (Lf[LIDX(6,4)]*y4 + Lf[LIDX(6,5)]*y5));
        const double y7 = x7 - ((((Lf[LIDX(7,0)]*y0 + Lf[LIDX(7,1)]*y1)
                                + (Lf[LIDX(7,2)]*y2 + Lf[LIDX(7,3)]*y3))
                                + (Lf[LIDX(7,4)]*y4 + Lf[LIDX(7,5)]*y5)) + Lf[LIDX(7,6)]*y6);
        const double y8 = x8 - ((((Lf[LIDX(8,0)]*y0 + Lf[LIDX(8,1)]*y1)
                                + (Lf[LIDX(8,2)]*y2 + Lf[LIDX(8,3)]*y3))
                                + ((Lf[LIDX(8,4)]*y4 + Lf[LIDX(8,5)]*y5) + Lf[LIDX(8,6)]*y6))
                                + Lf[LIDX(8,7)]*y7);
        // bwd: x = L^{-T} D^{-1} y  (unit upper), newest z shallow
        const double z8 = y8*Dinv[8];
        const double z7 = y7*Dinv[7] - Lf[LIDX(8,7)]*z8;
        const double z6 = y6*Dinv[6] - (Lf[LIDX(8,6)]*z8 + Lf[LIDX(7,6)]*z7);
        const double z5 = y5*Dinv[5] - ((Lf[LIDX(8,5)]*z8 + Lf[LIDX(7,5)]*z7)
                                        + Lf[LIDX(6,5)]*z6);
        const double z4 = y4*Dinv[4] - ((Lf[LIDX(8,4)]*z8 + Lf[LIDX(7,4)]*z7)
                                        + (Lf[LIDX(6,4)]*z6 + Lf[LIDX(5,4)]*z5));
        const double z3 = y3*Dinv[3] - (((Lf[LIDX(8,3)]*z8 + Lf[LIDX(7,3)]*z7)
                                        + (Lf[LIDX(6,3)]*z6 + Lf[LIDX(5,3)]*z5))
                                        + Lf[LIDX(4,3)]*z4);
        const double z2 = y2*Dinv[2] - (((Lf[LIDX(8,2)]*z8 + Lf[LIDX(7,2)]*z7)
                                        + (Lf[LIDX(6,2)]*z6 + Lf[LIDX(5,2)]*z5))
                                        + (Lf[LIDX(4,2)]*z4 + Lf[LIDX(3,2)]*z3));
        const double z1 = y1*Dinv[1] - ((((Lf[LIDX(8,1)]*z8 + Lf[LIDX(7,1)]*z7)
                                        + (Lf[LIDX(6,1)]*z6 + Lf[LIDX(5,1)]*z5))
                                        + (Lf[LIDX(4,1)]*z4 + Lf[LIDX(3,1)]*z3))
                                        + Lf[LIDX(2,1)]*z2);
        const double z0 = y0*Dinv[0] - ((((Lf[LIDX(8,0)]*z8 + Lf[LIDX(7,0)]*z7)
                                        + (Lf[LIDX(6,0)]*z6 + Lf[LIDX(5,0)]*z5))
                                        + (Lf[LIDX(4,0)]*z4 + Lf[LIDX(3,0)]*z3))
                                        + (Lf[LIDX(2,0)]*z2 + Lf[LIDX(1,0)]*z1));
        x0=z0; x1=z1; x2=z2; x3=z3; x4=z4; x5=z5; x6=z6; x7=z7; x8=z8;
    }
    {
        const double n = (((x0*x0 + x1*x1) + (x2*x2 + x3*x3))
                        + ((x4*x4 + x5*x5) + (x6*x6 + x7*x7))) + x8*x8;
        const double inv = 1.0 / sqrt(n);
        x0*=inv; x1*=inv; x2*=inv; x3*=inv; x4*=inv;
        x5*=inv; x6*=inv; x7*=inv; x8*=inv;
    }

    // ---- per-lane masked loss with in-register H ----
    double hs = 0.0, hc = 0.0, rs = 0.0;
    #pragma unroll
    for (int p = 0; p < 5; ++p) {
        const double px_ = Px[p], py_ = Py[p];
        const double gx = (double)gxr[p];
        const double gz = (double)gzr[p];
        const double nw0 = x0*px_ + x1*py_ + x2;
        const double nw1 = x3*px_ + x4*py_ + x5;
        const double nw2 = x6*px_ + x7*py_ + x8;
        const double inv = 1.0 / (nw2 + 1e-10);
        const double rx = nw0 * inv;
        const double rz = nw1 * inv;
        const bool msk = (rx > -40.0) && (rx < 40.0) && (rz > 0.0) && (rz < 80.0);
        if (msk) { hs += sl1(rx, gx) + sl1(rz, gz); hc += 2.0; }
        else     { rs += sl1((double)qx[p], gx) + sl1((double)qz[p], gz); }
    }

    #pragma unroll
    for (int off = 32; off > 0; off >>= 1) {
        hs += __shfl_xor(hs, off);
        hc += __shfl_xor(hc, off);
        rs += __shfl_xor(rs, off);
    }
    if (m == 0) {
        double* dst = partials + (size_t)(combo*BNUM + b) * 3;
        dst[0] = hs; dst[1] = hc; dst[2] = rs;
    }
}

// Single wave: fold 192x3 partials -> final scalar.
// Per combo HC+RC = 4096 elems * 10 = 40960 exactly (counts are integers).
__global__ __launch_bounds__(64) void finalize2(
    const double* __restrict__ partials, float* __restrict__ out)
{
    const int t = threadIdx.x;
    double acc[3][3];
    #pragma unroll
    for (int c = 0; c < 3; ++c)
        #pragma unroll
        for (int j = 0; j < 3; ++j)
            acc[c][j] = partials[(size_t)(c*BNUM + t) * 3 + j];

    #pragma unroll
    for (int off = 32; off > 0; off >>= 1) {
        #pragma unroll
        for (int c = 0; c < 3; ++c)
            #pragma unroll
            for (int j = 0; j < 3; ++j)
                acc[c][j] += __shfl_xor(acc[c][j], off);
    }
    if (t == 0) {
        double tot = 0.0;
        #pragma unroll
        for (int c = 0; c < 3; ++c) {
            const double hc = acc[c][1];
            const double rc = 40960.0 - hc;
            tot += acc[c][0] / fmax(hc, 1.0)
                 + 0.5 * (acc[c][2] / fmax(rc, 1.0));
        }
        out[0] = (float)(tot / 3.0);
    }
}

extern "C" void kernel_launch(void* const* d_in, const int* in_sizes, int n_in,
                              void* d_out, int out_size, void* d_ws, size_t ws_size,
                              hipStream_t stream)
{
    const float* center  = (const float*)d_in[1];
    const int*   cls     = (const int*)  d_in[2];
    const float* ry      = (const float*)d_in[3];
    const float* size3d  = (const float*)d_in[4];
    const float* Pgt     = (const float*)d_in[5];
    const float* Qgt     = (const float*)d_in[6];
    const float* off_gt  = (const float*)d_in[7];
    const float* dep_gt  = (const float*)d_in[8];
    const float* out_off = (const float*)d_in[9];
    const float* out_dep = (const float*)d_in[10];
    const float* calibs  = (const float*)d_in[11];
    const float* tinv    = (const float*)d_in[12];

    double* partials = (double*)d_ws;   // 192*3 doubles
    float*  out      = (float*)d_out;

    fused_kernel<<<dim3(BNUM,3), 64, 0, stream>>>(center, cls, ry, size3d, Pgt, Qgt,
        off_gt, dep_gt, out_off, out_dep, calibs, tinv, partials);
    finalize2<<<1, 64, 0, stream>>>(partials, out);
}

// Round 11
// 13.534 us; speedup vs baseline: 1.0572x; 1.0572x over previous
//
#include <hip/hip_runtime.h>
#include <math.h>

#define KTOT 4096
#define BNUM 64
#define MNUM 64
#define NITER 6

// packed lower-tri index (j<=i)
#define LIDX(i,j) ((i)*((i)+1)/2 + (j))

__device__ const float c_cls_mean[3][3] = {
    {1.76255119f, 0.66068622f, 0.84422524f},
    {1.52563191462f, 1.62856739989f, 3.88311640418f},
    {1.73698127f, 0.59706367f, 1.76282397f}
};

// symmetric-3x3 packed access: (0,0)=0 (0,1)=1 (0,2)=2 (1,1)=3 (1,2)=4 (2,2)=5
__device__ __forceinline__ double sym3(const double* a, int i, int j) {
    const int lo = i < j ? i : j, hi = i < j ? j : i;
    return a[lo == 0 ? hi : (lo == 1 ? hi + 2 : 5)];
}
// Full Gram accessor from the 24 unique entries.
// G = [[B, 0, U],[0, B, V],[U^T, V^T, D]]  (U,V stored WITH the minus sign)
__device__ __forceinline__ double Gat(const double* B, const double* U,
                                      const double* V, const double* D,
                                      int i, int j) {
    if (j < i) { const int t = i; i = j; j = t; }
    if (j < 3)  return sym3(B, i, j);
    if (j < 6)  return (i < 3) ? 0.0 : sym3(B, i - 3, j - 3);
    if (i < 3)  return sym3(U, i, j - 6);
    if (i < 6)  return sym3(V, i - 3, j - 6);
    return sym3(D, i - 6, j - 6);
}

// Compute the 5 Qpred (x,z) points for element k under combo c (f32, matches JAX).
__device__ __forceinline__ void compute_qpred(
    int k, int combo,
    const float* __restrict__ center, const int* __restrict__ cls_ids,
    const float* __restrict__ ry, const float* __restrict__ size3d,
    const float* __restrict__ off_gt, const float* __restrict__ dep_gt,
    const float* __restrict__ out_off, const float* __restrict__ out_dep,
    const float* __restrict__ calibs, const float* __restrict__ trans_inv,
    float* qx, float* qz)
{
    const int b = k >> 6;
    const float cx = center[2*k];
    const int cid = cls_ids[k];
    const float d1 = size3d[3*k+1] + c_cls_mean[cid][1];
    const float d2 = size3d[3*k+2] + c_cls_mean[cid][2];
    float sn, cs;
    sincosf(ry[k], &sn, &cs);

    const float* C = calibs + b*12;
    const float f  = C[0];
    const float cu = C[2];
    const float tx = C[3];
    const float t_x = -tx / f;

    const float* TI = trans_inv + b*6;
    const float s   = TI[0];
    const float t0x = TI[2];

    float ox, dep;
    if (combo == 0)      { ox = off_gt[2*k];  dep = out_dep[k]; }
    else if (combo == 1) { ox = out_off[2*k]; dep = dep_gt[k]; }
    else                 { ox = out_off[2*k]; dep = out_dep[k]; }

    const float uv4x = (cx + ox) * 4.0f;
    const float projx = s * uv4x + t0x;
    const float px = (projx - cu) * dep / f + t_x;
    const float Px = px;
    const float Pz = dep;

    const float r1t[4] = {0.5f, -0.5f, -0.5f, 0.5f};
    const float r2t[4] = {0.5f,  0.5f, -0.5f, -0.5f};
    qx[0] = Px; qz[0] = Pz;
    #pragma unroll
    for (int n = 0; n < 4; ++n) {
        const float sx = d2 * r2t[n];
        const float sz = d1 * r1t[n];
        qx[n+1] = Px + (cs*sx + sn*sz);
        qz[n+1] = Pz + (-sn*sx + cs*sz);
    }
}

__device__ __forceinline__ double sl1(double p, double t) {
    double d = p - t, ad = fabs(d);
    return ad < 1.0 ? 0.5*d*d : ad - 0.5;
}

// One block = one (batch, combo). Gram (24 unique) -> redundant per-lane
// LDL^T factorization + inverse iteration -> per-lane masked loss -> partial write.
__global__ __launch_bounds__(64, 1) void fused_kernel(
    const float* __restrict__ center, const int* __restrict__ cls_ids,
    const float* __restrict__ ry, const float* __restrict__ size3d,
    const float* __restrict__ Pgt, const float* __restrict__ Qgt,
    const float* __restrict__ off_gt, const float* __restrict__ dep_gt,
    const float* __restrict__ out_off, const float* __restrict__ out_dep,
    const float* __restrict__ calibs, const float* __restrict__ trans_inv,
    double* __restrict__ partials)
{
    const int b = blockIdx.x, combo = blockIdx.y;
    const int m = threadIdx.x;
    const int k = (b << 6) + m;

    float qx[5], qz[5];
    compute_qpred(k, combo, center, cls_ids, ry, size3d,
                  off_gt, dep_gt, out_off, out_dep, calibs, trans_inv, qx, qz);

    // ---- early loads: Pgt + Qgt into registers (latency hides under the
    //      butterfly + LDL^T ALU phase below) ----
    double Px[5], Py[5];
    float gxr[5], gzr[5];
    #pragma unroll
    for (int p = 0; p < 5; ++p) {
        const float2 P2 = *reinterpret_cast<const float2*>(&Pgt[(k*5+p)*2]);
        Px[p] = (double)P2.x;
        Py[p] = (double)P2.y;
        gxr[p] = Qgt[(k*5+p)*3 + 0];
        gzr[p] = Qgt[(k*5+p)*3 + 2];
    }

    // ---- Gram accumulation: 24 unique entries (B, U=-S_u, V=-S_v, D) ----
    double B[6], U[6], V[6], D[6];
    #pragma unroll
    for (int i = 0; i < 6; ++i) { B[i]=0.0; U[i]=0.0; V[i]=0.0; D[i]=0.0; }

    #pragma unroll
    for (int p = 0; p < 5; ++p) {
        const double x = Px[p];
        const double y = Py[p];
        const double u = (double)qx[p];
        const double v = (double)qz[p];
        const double w[6] = {x*x, x*y, x, y*y, y, 1.0};  // P (x) P packed sym
        const double uv2 = u*u + v*v;
        #pragma unroll
        for (int i = 0; i < 6; ++i) {
            B[i] += w[i];
            U[i] -= w[i]*u;
            V[i] -= w[i]*v;
            D[i] += w[i]*uv2;
        }
    }

    // ---- butterfly reduce (all lanes get full unique-Gram): 24 x 6 shfl ----
    #pragma unroll
    for (int off = 32; off > 0; off >>= 1) {
        #pragma unroll
        for (int i = 0; i < 6; ++i) {
            B[i] += __shfl_xor(B[i], off);
            U[i] += __shfl_xor(U[i], off);
            V[i] += __shfl_xor(V[i], off);
            D[i] += __shfl_xor(D[i], off);
        }
    }

    // ---- ridge shift on the diagonal (eigenvectors unchanged) ----
    double gmax = fmax(fmax(B[0], B[3]), fmax(B[5], fmax(D[0], fmax(D[3], D[5]))));
    const double ridge = 1e-10 * gmax;
    B[0] += ridge; B[3] += ridge; B[5] += ridge;
    D[0] += ridge; D[3] += ridge; D[5] += ridge;

    // ---- LDL^T: G = L D L^T, L unit-lower (off-diag packed), Dinv = 1/D ----
    // No f64 sqrt anywhere in the factorization chain.
    double Lf[45], Dinv[9];
    #pragma unroll
    for (int i = 0; i < 9; ++i) {
        double w[9];                 // w[t] = L_it * D_t for this row (== pre-division s)
        double diag = Gat(B, U, V, D, i, i);
        #pragma unroll
        for (int j = 0; j < 9; ++j) {
            if (j < i) {
                double s = Gat(B, U, V, D, j, i);
                #pragma unroll
                for (int t = 0; t < 9; ++t)
                    if (t < j) s -= Lf[LIDX(j,t)] * w[t];
                const double lij = s * Dinv[j];
                Lf[LIDX(i,j)] = lij;
                w[j] = s;
                diag -= lij * s;
            }
        }
        Dinv[i] = 1.0 / fmax(diag, ridge * 1e-2);   // pivot guard
    }

    // ---- inverse iteration, UNNORMALIZED; single normalization at end ----
    double x[9];
    #pragma unroll
    for (int j = 0; j < 9; ++j) x[j] = 1.0 + 0.0625 * j;

    #pragma unroll 1
    for (int it = 0; it < NITER; ++it) {
        double y[9];
        #pragma unroll
        for (int i = 0; i < 9; ++i) {          // fwd: unit lower
            double s = x[i];
            #pragma unroll
            for (int t = 0; t < 9; ++t)
                if (t < i) s -= Lf[LIDX(i,t)] * y[t];
            y[i] = s;
        }
        #pragma unroll
        for (int i = 8; i >= 0; --i) {         // diag + bwd: unit upper
            double s = y[i] * Dinv[i];
            #pragma unroll
            for (int t = 8; t > 0; --t)
                if (t > i) s -= Lf[LIDX(t,i)] * x[t];
            x[i] = s;                           // overwrite x with new iterate
        }
    }
    {
        double n = 0.0;
        #pragma unroll
        for (int j = 0; j < 9; ++j) n += x[j]*x[j];
        const double inv = 1.0 / sqrt(n);
        #pragma unroll
        for (int j = 0; j < 9; ++j) x[j] *= inv;
    }

    // ---- per-lane masked loss with in-register H = x ----
    double hs = 0.0, hc = 0.0, rs = 0.0;
    #pragma unroll
    for (int p = 0; p < 5; ++p) {
        const double px_ = Px[p], py_ = Py[p];
        const double gx = (double)gxr[p];
        const double gz = (double)gzr[p];
        const double nw0 = x[0]*px_ + x[1]*py_ + x[2];
        const double nw1 = x[3]*px_ + x[4]*py_ + x[5];
        const double nw2 = x[6]*px_ + x[7]*py_ + x[8];
        const double inv = 1.0 / (nw2 + 1e-10);
        const double rx = nw0 * inv;
        const double rz = nw1 * inv;
        const bool msk = (rx > -40.0) && (rx < 40.0) && (rz > 0.0) && (rz < 80.0);
        if (msk) { hs += sl1(rx, gx) + sl1(rz, gz); hc += 2.0; }
        else     { rs += sl1((double)qx[p], gx) + sl1((double)qz[p], gz); }
    }

    #pragma unroll
    for (int off = 32; off > 0; off >>= 1) {
        hs += __shfl_xor(hs, off);
        hc += __shfl_xor(hc, off);
        rs += __shfl_xor(rs, off);
    }
    if (m == 0) {
        double* dst = partials + (size_t)(combo*BNUM + b) * 3;
        dst[0] = hs; dst[1] = hc; dst[2] = rs;
    }
}

// Single wave: fold 192x3 partials -> final scalar.
// Per combo HC+RC = 4096 elems * 10 = 40960 exactly (counts are integers).
__global__ __launch_bounds__(64) void finalize2(
    const double* __restrict__ partials, float* __restrict__ out)
{
    const int t = threadIdx.x;
    double acc[3][3];
    #pragma unroll
    for (int c = 0; c < 3; ++c)
        #pragma unroll
        for (int j = 0; j < 3; ++j)
            acc[c][j] = partials[(size_t)(c*BNUM + t) * 3 + j];

    #pragma unroll
    for (int off = 32; off > 0; off >>= 1) {
        #pragma unroll
        for (int c = 0; c < 3; ++c)
            #pragma unroll
            for (int j = 0; j < 3; ++j)
                acc[c][j] += __shfl_xor(acc[c][j], off);
    }
    if (t == 0) {
        double tot = 0.0;
        #pragma unroll
        for (int c = 0; c < 3; ++c) {
            const double hc = acc[c][1];
            const double rc = 40960.0 - hc;
            tot += acc[c][0] / fmax(hc, 1.0)
                 + 0.5 * (acc[c][2] / fmax(rc, 1.0));
        }
        out[0] = (float)(tot / 3.0);
    }
}

extern "C" void kernel_launch(void* const* d_in, const int* in_sizes, int n_in,
                              void* d_out, int out_size, void* d_ws, size_t ws_size,
                              hipStream_t stream)
{
    const float* center  = (const float*)d_in[1];
    const int*   cls     = (const int*)  d_in[2];
    const float* ry      = (const float*)d_in[3];
    const float* size3d  = (const float*)d_in[4];
    const float* Pgt     = (const float*)d_in[5];
    const float* Qgt     = (const float*)d_in[6];
    const float* off_gt  = (const float*)d_in[7];
    const float* dep_gt  = (const float*)d_in[8];
    const float* out_off = (const float*)d_in[9];
    const float* out_dep = (const float*)d_in[10];
    const float* calibs  = (const float*)d_in[11];
    const float* tinv    = (const float*)d_in[12];

    double* partials = (double*)d_ws;   // 192*3 doubles
    float*  out      = (float*)d_out;

    fused_kernel<<<dim3(BNUM,3), 64, 0, stream>>>(center, cls, ry, size3d, Pgt, Qgt,
        off_gt, dep_gt, out_off, out_dep, calibs, tinv, partials);
    finalize2<<<1, 64, 0, stream>>>(partials, out);
}